// Round 3
// baseline (298.499 us; speedup 1.0000x reference)
//
#include <hip/hip_runtime.h>
#include <math.h>

typedef short s8v __attribute__((ext_vector_type(8)));
typedef float f4v __attribute__((ext_vector_type(4)));

#define HH 256
#define TP 16          // points per block
#define NTHREADS 256

// ---- bf16 split helpers (truncation split: x = hi + lo) ----
__device__ __forceinline__ unsigned short bf_hi(float x) {
    union { float f; unsigned u; } v; v.f = x;
    return (unsigned short)(v.u >> 16);
}
__device__ __forceinline__ float bf_hi_f(float x) {
    union { float f; unsigned u; } v; v.f = x;
    v.u &= 0xFFFF0000u;
    return v.f;
}
__device__ __forceinline__ float bf2f(unsigned short h) {
    union { unsigned u; float f; } v; v.u = ((unsigned)h) << 16;
    return v.f;
}
__device__ __forceinline__ unsigned pack_hi2(float x, float y) {
    return (unsigned)bf_hi(x) | ((unsigned)bf_hi(y) << 16);
}
__device__ __forceinline__ unsigned pack_lo2(float x, float y) {
    return (unsigned)bf_hi(x - bf_hi_f(x)) | ((unsigned)bf_hi(y - bf_hi_f(y)) << 16);
}

// ---- prep: W1..W3 -> hi/lo bf16 planes in B-fragment-linear order ----
// B frag: for (nt, ks): lane l holds W[nt*16 + (l&15)][ks*32 + (l>>4)*8 + j], j=0..7
// thread <-> (layer, n, kg): reads 8 consecutive k (coalesced), writes two 16B chunks
__global__ __launch_bounds__(256)
void prep_weights(const float* __restrict__ W1, const float* __restrict__ W2,
                  const float* __restrict__ W3, unsigned short* __restrict__ ws)
{
    int t = blockIdx.x * 256 + threadIdx.x;   // 0 .. 24575
    int layer = t >> 13;
    int rem = t & 8191;
    int n  = rem >> 5;
    int kg = rem & 31;                         // k-group of 8
    const float* W = (layer == 0) ? W1 : (layer == 1) ? W2 : W3;
    const float* src = W + n * HH + kg * 8;
    float4 x0 = *(const float4*)src;
    float4 x1 = *(const float4*)(src + 4);
    float xs[8] = {x0.x, x0.y, x0.z, x0.w, x1.x, x1.y, x1.z, x1.w};
    int ks = kg >> 2, quad = kg & 3;
    int l  = quad * 16 + (n & 15);
    int nt = n >> 4;
    int dst = ((nt * 8 + ks) * 64 + l) * 8;
    unsigned short* base = ws + layer * 131072;
    s8v hi, lo;
    #pragma unroll
    for (int j = 0; j < 8; ++j) {
        hi[j] = (short)bf_hi(xs[j]);
        lo[j] = (short)bf_hi(xs[j] - bf_hi_f(xs[j]));
    }
    *(s8v*)(base + dst)         = hi;
    *(s8v*)(base + 65536 + dst) = lo;
}

// ---- main fused kernel ----
// A planes in LDS are FRAGMENT-LINEAR: short idx = ((s*8+ks)*64 + lane)*8 + j
// (stream stride 4096 shorts, ks stride 512) -> MFMA-phase reads are wave-contiguous
__global__ __launch_bounds__(NTHREADS, 3)
void capnn_mfma(const float* __restrict__ inp,
                const float* __restrict__ W0, const float* __restrict__ b0,
                const float* __restrict__ b1, const float* __restrict__ b2,
                const float* __restrict__ b3,
                const float* __restrict__ W4, const float* __restrict__ b4,
                const float* __restrict__ lgr, const float* __restrict__ lcc,
                const float* __restrict__ lil,
                const float* __restrict__ imean, const float* __restrict__ istd,
                const float* __restrict__ tmean, const float* __restrict__ tstd,
                const unsigned short* __restrict__ wsW,
                float* __restrict__ out, int N)
{
    __shared__ __align__(16) unsigned short Ahi[12288];
    __shared__ __align__(16) unsigned short Alo[12288];
    __shared__ float sn_sh[TP], tn_sh[TP];
    __shared__ float head_s[48];

    const int tid  = threadIdx.x;
    const int lane = tid & 63;
    const int w    = tid >> 6;       // wave id: owns N cols [w*64, w*64+64)
    const int m16  = lane & 15;
    const int q    = lane >> 4;
    const int pbase = blockIdx.x * TP;

    // ---- stage normalized inputs ----
    if (tid < TP) {
        int pg = pbase + tid;
        float s = 0.f, t = 0.f;
        if (pg < N) { s = inp[2 * pg]; t = inp[2 * pg + 1]; }
        sn_sh[tid] = (s - imean[0]) / (istd[0] + 1e-8f);
        tn_sh[tid] = (t - imean[1]) / (istd[1] + 1e-8f);
    }
    __syncthreads();

    // ---- layer 0: 2 -> 256. thread <-> (l0, jp): writes are wave-contiguous b32 ----
    {
        const int l0 = tid >> 2, jp = tid & 3;
        const int p0 = l0 & 15, kq = l0 >> 4;
        const float sn = sn_sh[p0], tn = tn_sh[p0];
        unsigned* AhiW = (unsigned*)Ahi;
        unsigned* AloW = (unsigned*)Alo;
        #pragma unroll 2
        for (int ks = 0; ks < 8; ++ks) {
            const int n0 = ks * 32 + kq * 8 + jp * 2;
            float2 wa = ((const float2*)W0)[n0];
            float2 wb = ((const float2*)W0)[n0 + 1];
            float za = fmaf(wa.x, sn, fmaf(wa.y, tn, b0[n0]));
            float zb = fmaf(wb.x, sn, fmaf(wb.y, tn, b0[n0 + 1]));
            float ea = __expf(2.f * za), eb = __expf(2.f * zb);
            float aa = 1.f - 2.f * __builtin_amdgcn_rcpf(ea + 1.f);
            float ab = 1.f - 2.f * __builtin_amdgcn_rcpf(eb + 1.f);
            float ga = 1.f - aa * aa, gb = 1.f - ab * ab;
            float d1a = ga * wa.y,           d1b = gb * wb.y;
            float d2a = -2.f * aa * d1a * wa.y, d2b = -2.f * ab * d1b * wb.y;
            const int di = (ks * 64 + l0) * 4 + jp;   // dwords; stream stride 2048
            AhiW[di]        = pack_hi2(aa, ab);
            AloW[di]        = pack_lo2(aa, ab);
            AhiW[2048 + di] = pack_hi2(d1a, d1b);
            AloW[2048 + di] = pack_lo2(d1a, d1b);
            AhiW[4096 + di] = pack_hi2(d2a, d2b);
            AloW[4096 + di] = pack_lo2(d2a, d2b);
        }
    }
    __syncthreads();

    // ---- layers 1..3: (48x256) x (256x256)^T via split-bf16 MFMA ----
    for (int L = 0; L < 3; ++L) {
        const unsigned short* __restrict__ Wlh = wsW + L * 131072;
        const unsigned short* __restrict__ Wll = Wlh + 65536;
        const float* __restrict__ bL = (L == 0) ? b1 : (L == 1) ? b2 : b3;

        f4v acc[3][4];
        #pragma unroll
        for (int i = 0; i < 4; ++i) {
            float bias = bL[w * 64 + i * 16 + m16];
            acc[0][i] = (f4v){bias, bias, bias, bias};
            acc[1][i] = (f4v){0.f, 0.f, 0.f, 0.f};
            acc[2][i] = (f4v){0.f, 0.f, 0.f, 0.f};
        }

        #pragma unroll 2
        for (int ks = 0; ks < 8; ++ks) {
            s8v bh[4], bl[4];
            #pragma unroll
            for (int i = 0; i < 4; ++i) {
                int off = (((w * 4 + i) * 8 + ks) * 64 + lane) * 8;
                bh[i] = *(const s8v*)(Wlh + off);
                bl[i] = *(const s8v*)(Wll + off);
            }
            s8v ah[3], al[3];
            #pragma unroll
            for (int s = 0; s < 3; ++s) {
                int off = s * 4096 + ks * 512 + lane * 8;  // wave-contiguous 1024B
                ah[s] = *(const s8v*)&Ahi[off];
                al[s] = *(const s8v*)&Alo[off];
            }
            #pragma unroll
            for (int s = 0; s < 3; ++s)
                #pragma unroll
                for (int i = 0; i < 4; ++i)
                    acc[s][i] = __builtin_amdgcn_mfma_f32_16x16x32_bf16(ah[s], bh[i], acc[s][i], 0, 0, 0);
            #pragma unroll
            for (int s = 0; s < 3; ++s)
                #pragma unroll
                for (int i = 0; i < 4; ++i)
                    acc[s][i] = __builtin_amdgcn_mfma_f32_16x16x32_bf16(ah[s], bl[i], acc[s][i], 0, 0, 0);
            #pragma unroll
            for (int s = 0; s < 3; ++s)
                #pragma unroll
                for (int i = 0; i < 4; ++i)
                    acc[s][i] = __builtin_amdgcn_mfma_f32_16x16x32_bf16(al[s], bh[i], acc[s][i], 0, 0, 0);
        }
        __syncthreads();   // all waves done reading A before overwrite

        // ---- transform: C layout col(n)=m16, row(p)=q*4+r; write frag-linear A ----
        #pragma unroll
        for (int i = 0; i < 4; ++i) {
            const int n    = w * 64 + i * 16 + m16;
            const int ksw  = n >> 5;
            const int quad = (n >> 3) & 3;
            const int j    = n & 7;
            const int bidx = ksw * 512 + (quad * 16 + q * 4) * 8 + j;  // + r*8 + s*4096
            #pragma unroll
            for (int r = 0; r < 4; ++r) {
                float z  = acc[0][i][r];
                float z1 = acc[1][i][r];
                float z2 = acc[2][i][r];
                float e = __expf(2.f * z);
                float a = 1.f - 2.f * __builtin_amdgcn_rcpf(e + 1.f);  // tanh
                float g = 1.f - a * a;
                float d1 = g * z1;
                float d2 = fmaf(g, z2, -2.f * a * d1 * z1);
                int idx = bidx + r * 8;
                Ahi[idx]        = (unsigned short)bf_hi(a);
                Alo[idx]        = (unsigned short)bf_hi(a - bf_hi_f(a));
                Ahi[4096 + idx] = (unsigned short)bf_hi(d1);
                Alo[4096 + idx] = (unsigned short)bf_hi(d1 - bf_hi_f(d1));
                Ahi[8192 + idx] = (unsigned short)bf_hi(d2);
                Alo[8192 + idx] = (unsigned short)bf_hi(d2 - bf_hi_f(d2));
            }
        }
        __syncthreads();
    }

    // ---- head: 256 -> 1 per row (48 rows = 3 streams x 16 pts) ----
    if (tid < 192) {
        const int row = tid >> 2, sub = tid & 3;
        const int s = row >> 4, p = row & 15;
        float sum = 0.f;
        #pragma unroll
        for (int kk = 0; kk < 2; ++kk) {
            const int ks = sub * 2 + kk;
            #pragma unroll
            for (int quad = 0; quad < 4; ++quad) {
                int off = s * 4096 + ks * 512 + (quad * 16 + p) * 8;
                s8v h8 = *(const s8v*)&Ahi[off];
                s8v l8 = *(const s8v*)&Alo[off];
                int k0 = ks * 32 + quad * 8;
                float4 wA = *(const float4*)(W4 + k0);
                float4 wB = *(const float4*)(W4 + k0 + 4);
                sum = fmaf(wA.x, bf2f((unsigned short)h8[0]) + bf2f((unsigned short)l8[0]), sum);
                sum = fmaf(wA.y, bf2f((unsigned short)h8[1]) + bf2f((unsigned short)l8[1]), sum);
                sum = fmaf(wA.z, bf2f((unsigned short)h8[2]) + bf2f((unsigned short)l8[2]), sum);
                sum = fmaf(wA.w, bf2f((unsigned short)h8[3]) + bf2f((unsigned short)l8[3]), sum);
                sum = fmaf(wB.x, bf2f((unsigned short)h8[4]) + bf2f((unsigned short)l8[4]), sum);
                sum = fmaf(wB.y, bf2f((unsigned short)h8[5]) + bf2f((unsigned short)l8[5]), sum);
                sum = fmaf(wB.z, bf2f((unsigned short)h8[6]) + bf2f((unsigned short)l8[6]), sum);
                sum = fmaf(wB.w, bf2f((unsigned short)h8[7]) + bf2f((unsigned short)l8[7]), sum);
            }
        }
        sum += __shfl_xor(sum, 1);
        sum += __shfl_xor(sum, 2);
        if (sub == 0) head_s[row] = sum;
    }
    __syncthreads();

    // ---- Verhulst residuals + store ----
    if (tid < TP) {
        int pg = pbase + tid;
        if (pg < N) {
            float r_  = expf(-lgr[0]);
            float Kc  = 0.2f + 0.8f / (1.f + expf(-lcc[0]));
            float Cc  = 0.1f / (1.f + expf(-lil[0]));
            float kci = 1.f / (Kc - Cc);
            float ts = tstd[0], tm = tmean[0];
            float U   = (head_s[tid] + b4[0]) * ts + tm;
            float Ut  = head_s[TP + tid] * ts;
            float Utt = head_s[2 * TP + tid] * ts;
            float Um  = U - Cc;
            float G   = r_ * Um * (1.f - Um * kci);
            float Gt  = r_ * Ut * (1.f - 2.f * Um * kci);
            out[pg]         = U;
            out[N + pg]     = Ut - G;
            out[2 * N + pg] = Utt - Gt;
        }
    }
}

extern "C" void kernel_launch(void* const* d_in, const int* in_sizes, int n_in,
                              void* d_out, int out_size, void* d_ws, size_t ws_size,
                              hipStream_t stream) {
    const float* inp   = (const float*)d_in[0];
    const float* W0    = (const float*)d_in[1];
    const float* b0    = (const float*)d_in[2];
    const float* W1    = (const float*)d_in[3];
    const float* b1    = (const float*)d_in[4];
    const float* W2    = (const float*)d_in[5];
    const float* b2    = (const float*)d_in[6];
    const float* W3    = (const float*)d_in[7];
    const float* b3    = (const float*)d_in[8];
    const float* W4    = (const float*)d_in[9];
    const float* b4    = (const float*)d_in[10];
    const float* lgr   = (const float*)d_in[11];
    const float* lcc   = (const float*)d_in[12];
    const float* lil   = (const float*)d_in[13];
    const float* imean = (const float*)d_in[14];
    const float* istd  = (const float*)d_in[15];
    const float* tmean = (const float*)d_in[16];
    const float* tstd  = (const float*)d_in[17];

    unsigned short* wsW = (unsigned short*)d_ws;   // 3 layers * 256KB hi/lo planes

    const int N = in_sizes[0] / 2;                 // 65536 points
    const int gridMain = (N + TP - 1) / TP;        // 4096 blocks

    hipLaunchKernelGGL(prep_weights, dim3(96), dim3(256), 0, stream, W1, W2, W3, wsW);
    hipLaunchKernelGGL(capnn_mfma, dim3(gridMain), dim3(NTHREADS), 0, stream,
                       inp, W0, b0, b1, b2, b3, W4, b4,
                       lgr, lcc, lil, imean, istd, tmean, tstd,
                       wsW, (float*)d_out, N);
}

// Round 4
// 282.122 us; speedup vs baseline: 1.0581x; 1.0581x over previous
//
#include <hip/hip_runtime.h>
#include <math.h>

typedef short s8v __attribute__((ext_vector_type(8)));
typedef float f4v __attribute__((ext_vector_type(4)));

#define HH 256
#define TP 16
#define NTHREADS 256
// LDS strides in SHORTS. ks-chunk = 64 rows * 8 shorts + 8 pad = 520 (1040 B,
// 16 B misalign per ks rotates banks -> conflict-free b64 scatter writes)
#define KSTR 520
#define SSTR 4160          // 8 * KSTR, per-stream
#define PLANE 12480        // 3 * SSTR shorts per plane

__device__ __forceinline__ unsigned short bf_hi(float x){ union{float f;unsigned u;}v; v.f=x; return (unsigned short)(v.u>>16); }
__device__ __forceinline__ float bf_hi_f(float x){ union{float f;unsigned u;}v; v.f=x; v.u &= 0xFFFF0000u; return v.f; }
__device__ __forceinline__ float bf2f(unsigned short h){ union{unsigned u;float f;}v; v.u=((unsigned)h)<<16; return v.f; }
__device__ __forceinline__ unsigned f2u(float x){ union{float f;unsigned u;}v; v.f=x; return v.u; }
// dst = [top16(b) : top16(a)]  (one v_perm_b32)
__device__ __forceinline__ unsigned pack_tops(float a, float b){
    return __builtin_amdgcn_perm(f2u(b), f2u(a), 0x07060302u);
}

// ---- prep: B-fragments for W1..W3 with k-permutation pi folded in, plus
// pi-ordered planes for W0 cols, b0, W4.
// pi(n): ks=n&7, quad=n>>6, j=((n>>4)&3)+4*((n>>3)&1); pi^-1(ks,quad,j) =
// quad*64 + (j&3)*16 + (j>>2)*8 + ks.
__global__ __launch_bounds__(256)
void prep_weights(const float* __restrict__ W1, const float* __restrict__ W2,
                  const float* __restrict__ W3, const float* __restrict__ W0,
                  const float* __restrict__ b0, const float* __restrict__ W4,
                  unsigned short* __restrict__ wsB, float* __restrict__ wsF)
{
    int t = blockIdx.x * 256 + threadIdx.x;
    if (t < 24576) {
        int layer = t >> 13;
        int rem = t & 8191;
        int l  = rem & 63;
        int ks = (rem >> 6) & 7;
        int nt = rem >> 9;
        const float* W = (layer == 0) ? W1 : (layer == 1) ? W2 : W3;
        int n_out = nt * 16 + (l & 15);
        int quad  = l >> 4;
        const float* row = W + n_out * HH;
        s8v hi, lo;
        #pragma unroll
        for (int j = 0; j < 8; ++j) {
            int n_in = quad * 64 + (j & 3) * 16 + ((j >> 2) << 3) + ks;
            float x = row[n_in];
            hi[j] = (short)bf_hi(x);
            lo[j] = (short)bf_hi(x - bf_hi_f(x));
        }
        int dst = ((nt * 8 + ks) * 64 + l) * 8;
        unsigned short* base = wsB + layer * 131072;
        *(s8v*)(base + dst)         = hi;
        *(s8v*)(base + 65536 + dst) = lo;
    } else if (t < 24832) {
        int n = t - 24576;
        int pos = ((n & 7) * 4 + (n >> 6)) * 8 + ((n >> 4) & 3) + 4 * ((n >> 3) & 1);
        wsF[pos]       = W0[2 * n];
        wsF[256 + pos] = W0[2 * n + 1];
        wsF[512 + pos] = b0[n];
        wsF[768 + pos] = W4[n];
    }
}

// ---- main fused kernel ----
// A planes (hi, lo) hold, per (stream s, ks): 64 rows (l = p + 16*quad) x 8
// shorts (j). MFMA step ks, lane l reads 16 B at s*SSTR + ks*KSTR + l*8: the
// feature there is pi^-1(ks, l>>4, j), matching the pi-permuted B fragments.
__global__ __launch_bounds__(NTHREADS, 3)
void capnn_mfma(const float* __restrict__ inp,
                const float* __restrict__ b1, const float* __restrict__ b2,
                const float* __restrict__ b3, const float* __restrict__ b4,
                const float* __restrict__ lgr, const float* __restrict__ lcc,
                const float* __restrict__ lil,
                const float* __restrict__ imean, const float* __restrict__ istd,
                const float* __restrict__ tmean, const float* __restrict__ tstd,
                const unsigned short* __restrict__ wsW,
                const float* __restrict__ wsF,
                float* __restrict__ out, int N)
{
    __shared__ __align__(16) unsigned short Ahi[PLANE];
    __shared__ __align__(16) unsigned short Alo[PLANE];
    __shared__ float sn_sh[TP], tn_sh[TP];
    __shared__ float head_s[48];

    const int tid  = threadIdx.x;
    const int lane = tid & 63;
    const int w    = tid >> 6;
    const int m16  = lane & 15;
    const int q    = lane >> 4;
    const int pbase = blockIdx.x * TP;

    const float* __restrict__ w00p = wsF;
    const float* __restrict__ w01p = wsF + 256;
    const float* __restrict__ b0p  = wsF + 512;
    const float* __restrict__ W4p  = wsF + 768;

    if (tid < TP) {
        int pg = pbase + tid;
        float s = 0.f, t = 0.f;
        if (pg < N) { s = inp[2 * pg]; t = inp[2 * pg + 1]; }
        sn_sh[tid] = (s - imean[0]) / (istd[0] + 1e-8f);
        tn_sh[tid] = (t - imean[1]) / (istd[1] + 1e-8f);
    }
    __syncthreads();

    // ---- layer 0: thread <-> (ks = wv+4g, row l). writes wave-contiguous b128
    {
        const int l  = tid & 63;
        const int wv = tid >> 6;
        const int p0 = l & 15, quad = l >> 4;
        const float sn = sn_sh[p0], tn = tn_sh[p0];
        #pragma unroll
        for (int g2 = 0; g2 < 2; ++g2) {
            const int ks = wv + 4 * g2;
            const int pos = (ks * 4 + quad) * 8;
            float4 wA0 = *(const float4*)(w00p + pos);
            float4 wA1 = *(const float4*)(w00p + pos + 4);
            float4 wB0 = *(const float4*)(w01p + pos);
            float4 wB1 = *(const float4*)(w01p + pos + 4);
            float4 bb0 = *(const float4*)(b0p + pos);
            float4 bb1 = *(const float4*)(b0p + pos + 4);
            float w00v[8] = {wA0.x,wA0.y,wA0.z,wA0.w,wA1.x,wA1.y,wA1.z,wA1.w};
            float w01v[8] = {wB0.x,wB0.y,wB0.z,wB0.w,wB1.x,wB1.y,wB1.z,wB1.w};
            float b0v[8]  = {bb0.x,bb0.y,bb0.z,bb0.w,bb1.x,bb1.y,bb1.z,bb1.w};
            float av[8], d1v[8], d2v[8];
            #pragma unroll
            for (int j = 0; j < 8; ++j) {
                float z = fmaf(w00v[j], sn, fmaf(w01v[j], tn, b0v[j]));
                float e = __expf(2.f * z);
                float a = 1.f - 2.f * __builtin_amdgcn_rcpf(e + 1.f);
                float g = 1.f - a * a;
                float d1 = g * w01v[j];
                float d2 = -2.f * a * d1 * w01v[j];
                av[j] = a; d1v[j] = d1; d2v[j] = d2;
            }
            const int base = ks * KSTR + l * 8;
            #pragma unroll
            for (int s = 0; s < 3; ++s) {
                const float* V = (s == 0) ? av : (s == 1) ? d1v : d2v;
                int4 hi4, lo4;
                hi4.x = (int)pack_tops(V[0], V[1]); hi4.y = (int)pack_tops(V[2], V[3]);
                hi4.z = (int)pack_tops(V[4], V[5]); hi4.w = (int)pack_tops(V[6], V[7]);
                float l0=V[0]-bf_hi_f(V[0]), l1=V[1]-bf_hi_f(V[1]);
                float l2=V[2]-bf_hi_f(V[2]), l3=V[3]-bf_hi_f(V[3]);
                float l4=V[4]-bf_hi_f(V[4]), l5=V[5]-bf_hi_f(V[5]);
                float l6=V[6]-bf_hi_f(V[6]), l7=V[7]-bf_hi_f(V[7]);
                lo4.x = (int)pack_tops(l0, l1); lo4.y = (int)pack_tops(l2, l3);
                lo4.z = (int)pack_tops(l4, l5); lo4.w = (int)pack_tops(l6, l7);
                *(int4*)&Ahi[s * SSTR + base] = hi4;
                *(int4*)&Alo[s * SSTR + base] = lo4;
            }
        }
    }
    __syncthreads();

    // ---- layers 1..3 ----
    for (int L = 0; L < 3; ++L) {
        const unsigned short* __restrict__ Wlh = wsW + L * 131072;
        const unsigned short* __restrict__ Wll = Wlh + 65536;
        const float* __restrict__ bL = (L == 0) ? b1 : (L == 1) ? b2 : b3;

        f4v acc[3][4];
        #pragma unroll
        for (int i = 0; i < 4; ++i) {
            float bias = bL[w * 64 + i * 16 + m16];
            acc[0][i] = (f4v){bias, bias, bias, bias};
            acc[1][i] = (f4v){0.f, 0.f, 0.f, 0.f};
            acc[2][i] = (f4v){0.f, 0.f, 0.f, 0.f};
        }

        #pragma unroll 2
        for (int ks = 0; ks < 8; ++ks) {
            s8v bh[4], bl[4];
            #pragma unroll
            for (int i = 0; i < 4; ++i) {
                int off = (((w * 4 + i) * 8 + ks) * 64 + lane) * 8;
                bh[i] = *(const s8v*)(Wlh + off);
                bl[i] = *(const s8v*)(Wll + off);
            }
            s8v ah[3], al[3];
            const int aoff = ks * KSTR + lane * 8;
            #pragma unroll
            for (int s = 0; s < 3; ++s) {
                ah[s] = *(const s8v*)&Ahi[s * SSTR + aoff];
                al[s] = *(const s8v*)&Alo[s * SSTR + aoff];
            }
            #pragma unroll
            for (int s = 0; s < 3; ++s)
                #pragma unroll
                for (int i = 0; i < 4; ++i)
                    acc[s][i] = __builtin_amdgcn_mfma_f32_16x16x32_bf16(ah[s], bh[i], acc[s][i], 0, 0, 0);
            #pragma unroll
            for (int s = 0; s < 3; ++s)
                #pragma unroll
                for (int i = 0; i < 4; ++i)
                    acc[s][i] = __builtin_amdgcn_mfma_f32_16x16x32_bf16(ah[s], bl[i], acc[s][i], 0, 0, 0);
            #pragma unroll
            for (int s = 0; s < 3; ++s)
                #pragma unroll
                for (int i = 0; i < 4; ++i)
                    acc[s][i] = __builtin_amdgcn_mfma_f32_16x16x32_bf16(al[s], bh[i], acc[s][i], 0, 0, 0);
        }
        __syncthreads();   // all waves done reading A

        // ---- transform + pi-scatter: per (s,r,plane) one b64 (4 consecutive j)
        {
            const int ksw  = m16 & 7;
            const int hsel = m16 >> 3;
            const int wbase = ksw * KSTR + (16 * w + q * 4) * 8 + 4 * hsel;
            #pragma unroll
            for (int r = 0; r < 4; ++r) {
                float Av[3][4];
                #pragma unroll
                for (int i = 0; i < 4; ++i) {
                    float z  = acc[0][i][r];
                    float z1 = acc[1][i][r];
                    float z2 = acc[2][i][r];
                    float e = __expf(2.f * z);
                    float a = 1.f - 2.f * __builtin_amdgcn_rcpf(e + 1.f);
                    float g = 1.f - a * a;
                    float d1 = g * z1;
                    float d2 = fmaf(g, z2, -2.f * a * d1 * z1);
                    Av[0][i] = a; Av[1][i] = d1; Av[2][i] = d2;
                }
                #pragma unroll
                for (int s = 0; s < 3; ++s) {
                    float v0 = Av[s][0], v1 = Av[s][1], v2 = Av[s][2], v3 = Av[s][3];
                    int2 hi2, lo2;
                    hi2.x = (int)pack_tops(v0, v1); hi2.y = (int)pack_tops(v2, v3);
                    float l0 = v0 - bf_hi_f(v0), l1 = v1 - bf_hi_f(v1);
                    float l2 = v2 - bf_hi_f(v2), l3 = v3 - bf_hi_f(v3);
                    lo2.x = (int)pack_tops(l0, l1); lo2.y = (int)pack_tops(l2, l3);
                    const int idx = s * SSTR + wbase + r * 8;
                    *(int2*)&Ahi[idx] = hi2;
                    *(int2*)&Alo[idx] = lo2;
                }
            }
        }
        __syncthreads();
    }

    // ---- head: 256 -> 1 per row (48 rows = 3 streams x 16 pts) ----
    if (tid < 192) {
        const int row = tid >> 2, sub = tid & 3;
        const int s = row >> 4, p = row & 15;
        float sum = 0.f;
        #pragma unroll
        for (int kk = 0; kk < 2; ++kk) {
            const int ks = sub * 2 + kk;
            #pragma unroll
            for (int quad = 0; quad < 4; ++quad) {
                const int l = p + 16 * quad;
                const int off = s * SSTR + ks * KSTR + l * 8;
                s8v h8 = *(const s8v*)&Ahi[off];
                s8v l8 = *(const s8v*)&Alo[off];
                const float* w4 = W4p + (ks * 4 + quad) * 8;
                float4 wA = *(const float4*)w4;
                float4 wB = *(const float4*)(w4 + 4);
                sum = fmaf(wA.x, bf2f((unsigned short)h8[0]) + bf2f((unsigned short)l8[0]), sum);
                sum = fmaf(wA.y, bf2f((unsigned short)h8[1]) + bf2f((unsigned short)l8[1]), sum);
                sum = fmaf(wA.z, bf2f((unsigned short)h8[2]) + bf2f((unsigned short)l8[2]), sum);
                sum = fmaf(wA.w, bf2f((unsigned short)h8[3]) + bf2f((unsigned short)l8[3]), sum);
                sum = fmaf(wB.x, bf2f((unsigned short)h8[4]) + bf2f((unsigned short)l8[4]), sum);
                sum = fmaf(wB.y, bf2f((unsigned short)h8[5]) + bf2f((unsigned short)l8[5]), sum);
                sum = fmaf(wB.z, bf2f((unsigned short)h8[6]) + bf2f((unsigned short)l8[6]), sum);
                sum = fmaf(wB.w, bf2f((unsigned short)h8[7]) + bf2f((unsigned short)l8[7]), sum);
            }
        }
        sum += __shfl_xor(sum, 1);
        sum += __shfl_xor(sum, 2);
        if (sub == 0) head_s[row] = sum;
    }
    __syncthreads();

    if (tid < TP) {
        int pg = pbase + tid;
        if (pg < N) {
            float r_  = expf(-lgr[0]);
            float Kc  = 0.2f + 0.8f / (1.f + expf(-lcc[0]));
            float Cc  = 0.1f / (1.f + expf(-lil[0]));
            float kci = 1.f / (Kc - Cc);
            float ts = tstd[0], tm = tmean[0];
            float U   = (head_s[tid] + b4[0]) * ts + tm;
            float Ut  = head_s[TP + tid] * ts;
            float Utt = head_s[2 * TP + tid] * ts;
            float Um  = U - Cc;
            float G   = r_ * Um * (1.f - Um * kci);
            float Gt  = r_ * Ut * (1.f - 2.f * Um * kci);
            out[pg]         = U;
            out[N + pg]     = Ut - G;
            out[2 * N + pg] = Utt - Gt;
        }
    }
}

extern "C" void kernel_launch(void* const* d_in, const int* in_sizes, int n_in,
                              void* d_out, int out_size, void* d_ws, size_t ws_size,
                              hipStream_t stream) {
    const float* inp   = (const float*)d_in[0];
    const float* W0    = (const float*)d_in[1];
    const float* b0    = (const float*)d_in[2];
    const float* W1    = (const float*)d_in[3];
    const float* b1    = (const float*)d_in[4];
    const float* W2    = (const float*)d_in[5];
    const float* b2    = (const float*)d_in[6];
    const float* W3    = (const float*)d_in[7];
    const float* b3    = (const float*)d_in[8];
    const float* W4    = (const float*)d_in[9];
    const float* b4    = (const float*)d_in[10];
    const float* lgr   = (const float*)d_in[11];
    const float* lcc   = (const float*)d_in[12];
    const float* lil   = (const float*)d_in[13];
    const float* imean = (const float*)d_in[14];
    const float* istd  = (const float*)d_in[15];
    const float* tmean = (const float*)d_in[16];
    const float* tstd  = (const float*)d_in[17];

    unsigned short* wsB = (unsigned short*)d_ws;            // 768 KB B-frags
    float* wsF = (float*)((char*)d_ws + 786432);            // 4 KB pi-planes

    const int N = in_sizes[0] / 2;
    const int gridMain = (N + TP - 1) / TP;

    hipLaunchKernelGGL(prep_weights, dim3(97), dim3(256), 0, stream,
                       W1, W2, W3, W0, b0, W4, wsB, wsF);
    hipLaunchKernelGGL(capnn_mfma, dim3(gridMain), dim3(NTHREADS), 0, stream,
                       inp, b1, b2, b3, b4,
                       lgr, lcc, lil, imean, istd, tmean, tstd,
                       wsB, wsF, (float*)d_out, N);
}